// Round 15
// baseline (20257.202 us; speedup 1.0000x reference)
//
#include <hip/hip_runtime.h>
#include <hip/hip_fp16.h>
#include <math.h>

#define HN 1024
#define FN 256
#define LN 4096
#define NBLK 256
#define NTHR 512
#define NSLOT (LN - 1)   // 4095 sequential steps

// ws layout (u64 indices)  — EXACT r10 layout (packed: 4 units / 64B line):
//   wq[2][1024][2]  at 0     : self-tagged per-unit word pairs (4096 u64)
//     wordA = i16 | f16<<16 | g16<<32 | ep16<<48   (pg1 pre-acts of step ep)
//     wordB = o16 | h2_16<<16 | ep16<<48           (o pre-act step ep, h2(ep-1))
//     unit u's pair is 16B-aligned -> polled with ONE global_load_dwordx4
//   abort u32       at u64 index 4608

typedef unsigned long long u64;
typedef unsigned uv4 __attribute__((ext_vector_type(4)));

__device__ __forceinline__ float sigm(float x) { return 1.0f / (1.0f + __expf(-x)); }
__device__ __forceinline__ float tanh_f(float x) {
    x = fminf(fmaxf(x, -15.0f), 15.0f);
    float e = __expf(2.0f * x);
    return (e - 1.0f) / (e + 1.0f);
}
__device__ __forceinline__ u64 f2hb(float x) {
    union { __half h; unsigned short u; } c; c.h = __float2half(x); return (u64)c.u;
}
__device__ __forceinline__ float hbf(u64 w, int sh) {   // fp16 bits [sh,sh+16) -> f32
    union { unsigned short u; __half h; } c; c.u = (unsigned short)(w >> sh);
    return __half2float(c.h);
}
__device__ __forceinline__ __half2 u2h2(unsigned v) {
    union { unsigned u; __half2 h; } c; c.u = v; return c.h;
}
__device__ __forceinline__ unsigned pk2(float a, float b) {
    union { __half2 h; unsigned u; } c; c.h = __floats2half2_rn(a, b); return c.u;
}
__device__ __forceinline__ uint4 pack8(const float* p) {   // 8 f32 -> 8 fp16 (4 VGPRs)
    uint4 r;
    r.x = pk2(p[0], p[1]); r.y = pk2(p[2], p[3]);
    r.z = pk2(p[4], p[5]); r.w = pk2(p[6], p[7]);
    return r;
}
// 8-term fp16 dot via packed v_pk_fma_f16, f32 master accumulate
__device__ __forceinline__ float dot8(uint4 w, uint4 x, float acc) {
    __half2 s = __hmul2(u2h2(w.x), u2h2(x.x));
    s = __hfma2(u2h2(w.y), u2h2(x.y), s);
    s = __hfma2(u2h2(w.z), u2h2(x.z), s);
    s = __hfma2(u2h2(w.w), u2h2(x.w), s);
    return acc + __low2float(s) + __high2float(s);
}

// Issue two coherent 16B pair-loads WITHOUT waiting.
__device__ __forceinline__ void cpoll_issue(unsigned long long a0, unsigned long long a1,
                                            uv4& va, uv4& vb) {
    asm volatile("global_load_dwordx4 %0, %2, off sc0 sc1\n\t"
                 "global_load_dwordx4 %1, %3, off sc0 sc1"
                 : "=&v"(va), "=&v"(vb)
                 : "v"(a0), "v"(a1)
                 : "memory");
}
// Simple issue+wait pair load (r10 semantics) — used in the epilogue.
__device__ __forceinline__ void cpoll2(unsigned long long a0, unsigned long long a1,
                                       uv4& va, uv4& vb) {
    asm volatile("global_load_dwordx4 %0, %2, off sc0 sc1\n\t"
                 "global_load_dwordx4 %1, %3, off sc0 sc1\n\t"
                 "s_waitcnt vmcnt(0)"
                 : "=&v"(va), "=&v"(vb)
                 : "v"(a0), "v"(a1)
                 : "memory");
}
__device__ __forceinline__ void cstore4(unsigned long long addr, u64 A, u64 B) {
    uv4 pv;
    pv[0] = (unsigned)A; pv[1] = (unsigned)(A >> 32);
    pv[2] = (unsigned)B; pv[3] = (unsigned)(B >> 32);
    asm volatile("global_store_dwordx4 %0, %1, off sc0 sc1"
                 :: "v"(addr), "v"(pv) : "memory");
}

__global__ void ws_init(float* ws) {
    if (threadIdx.x == 0) *((unsigned*)((u64*)ws + 4608)) = 0u;   // abort flag
}

// 2nd arg = min waves per SIMD(EU): 2 waves/SIMD == 1 block/CU.
__global__ __launch_bounds__(NTHR, 2)
void lstm_main(const float* __restrict__ feat, const float* __restrict__ tgt,
               const float* __restrict__ Wih1, const float* __restrict__ bih1,
               const float* __restrict__ Whh1, const float* __restrict__ bhh1,
               const float* __restrict__ Wih2, const float* __restrict__ bih2,
               const float* __restrict__ Whh2, const float* __restrict__ bhh2,
               const float* __restrict__ Wout, const float* __restrict__ bout,
               float* __restrict__ out, float* __restrict__ ws)
{
    // block b owns units [4b,4b+4) of layer1 (16 gate rows) and layer2.
    // thread: lr = tid>>5 (row 0..15), sub = tid&31 (32-way K-split).
    __shared__ __align__(16) __half wc4[4 * HN];     //  8 KB  W_ih1[:,256], [unit][gate]
    __shared__ __align__(16) float  wout_s[HN];      //  4 KB
    __shared__ __align__(16) __half h1h[HN];         //  2 KB
    __shared__ __align__(16) __half h2h[HN];         //  2 KB
    __shared__ __align__(16) __half fh[FN];          //  0.5 KB
    __shared__ float b1s[16], b2s[16], g1s[16], g2s[16];
    __shared__ float rsum[NTHR / 64];
    __shared__ float bouts;
    __shared__ unsigned s_bad;

    const int tid = threadIdx.x;
    const int b4  = (int)blockIdx.x * 4;
    u64* wq  = (u64*)ws;
    unsigned* abop = (unsigned*)(wq + 4608);

    const int lr  = tid >> 5;          // gate row 0..15 (g*4+ui)
    const int sub = tid & 31;
    const int o8  = sub * 8;
    const int gr  = (lr >> 2) * HN + b4 + (lr & 3);   // global gate row

    // ---------------- prologue: weight slices (cache-served, fp16-packed) ----------------
    uint4 wf_r = pack8(Wih1 + (size_t)gr * (FN + 1) + o8);
    uint4 w1h_r[4], w2i_r[4], w2h_r[4];
    #pragma unroll
    for (int j = 0; j < 4; ++j) {
        const int c0 = o8 + j * 256;
        w1h_r[j] = pack8(Whh1 + (size_t)gr * HN + c0);
        w2i_r[j] = pack8(Wih2 + (size_t)gr * HN + c0);
        w2h_r[j] = pack8(Whh2 + (size_t)gr * HN + c0);
    }
    for (int e = tid; e < 4 * HN; e += NTHR) {
        int u = e >> 2, g = e & 3;
        wc4[e] = __float2half(Wih1[(g * HN + u) * (FN + 1) + FN]);
    }
    for (int e = tid; e < HN; e += NTHR) wout_s[e] = Wout[e];
    if (tid < 16) {
        int grr = (tid >> 2) * HN + b4 + (tid & 3);
        b1s[tid] = bih1[grr] + bhh1[grr];
        b2s[tid] = bih2[grr] + bhh2[grr];
    }
    if (tid == 0) { bouts = bout[0]; s_bad = 0u; }
    if (tid < FN) fh[tid] = __float2half(feat[tid]);
    __syncthreads();

    // priming: pg1(0) = W_ih1[:, :256] @ f_0 + biases  (h1_{-1} = 0)
    {
        uint4 fc = *reinterpret_cast<const uint4*>(&fh[o8]);
        float acc = dot8(wf_r, fc, 0.f);
        #pragma unroll
        for (int m = 1; m <= 16; m <<= 1) acc += __shfl_xor(acc, m);
        if (sub == 0) g1s[lr] = acc + b1s[lr];
    }
    __syncthreads();
    if (tid < 4) {   // publish {pg1(0), h2(-1)=0} ep=0 -> parity 0, one 16B store
        u64 A = f2hb(g1s[tid]) | (f2hb(g1s[4 + tid]) << 16) | (f2hb(g1s[8 + tid]) << 32);
        u64 B = f2hb(g1s[12 + tid]);
        cstore4((unsigned long long)(wq + (size_t)(b4 + tid) * 2), A, B);
    }

    float c1a = 0.f, c1b = 0.f;     // replicated c1 (units tid, tid+512)
    float c2v = 0.f;                // c2 for unit b4+tid (tid<4)
    float p = tgt[0];
    float lacc = 0.f;

    for (int s = 0; s < NSLOT; ++s) {
        const int par = s & 1;
        const int u0 = tid, u1 = tid + NTHR;

        // ---- feature prefetch (hides under the poll) ----
        float fv = (tid < FN) ? feat[(size_t)(s + 1) * FN + tid] : 0.f;

        // ---- 2-deep pipelined self-tagged poll (race-fixed) ----
        // vmcnt retires in issue order -> vmcnt(2) == "oldest pair done".
        // Extraction happens INSIDE each success branch, from the pair that
        // passed: at the X-check nothing in flight targets va/vb; at the
        // Y-check only va/vb are in flight and we read wa/wb. No cross-pair
        // register copies (r14's `va = wa` raced the in-flight writeback).
        u64 wA0 = 0, wB0 = 0, wA1 = 0, wB1 = 0;
        uv4 va, vb, wa, wb;
        {
            const u64* q = wq + (size_t)par * 2048;
            const unsigned long long a0 = (unsigned long long)(q + 2 * (size_t)u0);
            const unsigned long long a1 = (unsigned long long)(q + 2 * (size_t)u1);
            const unsigned need = (unsigned)s;
            cpoll_issue(a0, a1, va, vb);   // pair X
            cpoll_issue(a0, a1, wa, wb);   // pair Y
            unsigned it = 0;
            for (;;) {
                asm volatile("s_waitcnt vmcnt(2)" : "+v"(va), "+v"(vb) :: "memory");
                if (((va[1] >> 16) == need) && ((va[3] >> 16) == need) &&
                    ((vb[1] >> 16) == need) && ((vb[3] >> 16) == need)) {
                    wA0 = (u64)va[0] | ((u64)va[1] << 32);
                    wB0 = (u64)va[2] | ((u64)va[3] << 32);
                    wA1 = (u64)vb[0] | ((u64)vb[1] << 32);
                    wB1 = (u64)vb[2] | ((u64)vb[3] << 32);
                    break;
                }
                cpoll_issue(a0, a1, va, vb);
                asm volatile("s_waitcnt vmcnt(2)" : "+v"(wa), "+v"(wb) :: "memory");
                if (((wa[1] >> 16) == need) && ((wa[3] >> 16) == need) &&
                    ((wb[1] >> 16) == need) && ((wb[3] >> 16) == need)) {
                    wA0 = (u64)wa[0] | ((u64)wa[1] << 32);
                    wB0 = (u64)wa[2] | ((u64)wa[3] << 32);
                    wA1 = (u64)wb[0] | ((u64)wb[1] << 32);
                    wB1 = (u64)wb[2] | ((u64)wb[3] << 32);
                    break;
                }
                cpoll_issue(a0, a1, wa, wb);
                if (((++it) & 511u) == 0u) {
                    if (__hip_atomic_load(abop, __ATOMIC_RELAXED, __HIP_MEMORY_SCOPE_AGENT) != 0u
                        || it > (1u << 15)) {
                        __hip_atomic_store(abop, 1u, __ATOMIC_RELAXED, __HIP_MEMORY_SCOPE_AGENT);
                        s_bad = 1u;
                        break;
                    }
                }
            }
        }

        // ---- phase A: stage h2/f to LDS, pred(s-1) from local wout dot ----
        float h2v0 = hbf(wB0, 16);
        float h2v1 = hbf(wB1, 16);
        h2h[u0] = __float2half(h2v0);
        h2h[u1] = __float2half(h2v1);
        if (tid < FN) fh[tid] = __float2half(fv);
        float pp = wout_s[u0] * h2v0 + wout_s[u1] * h2v1;
        #pragma unroll
        for (int m = 1; m <= 32; m <<= 1) pp += __shfl_xor(pp, m);
        if ((tid & 63) == 0) rsum[tid >> 6] = pp;
        __syncthreads();
        if (s_bad != 0u) return;
        float dred = rsum[0] + rsum[1] + rsum[2] + rsum[3]
                   + rsum[4] + rsum[5] + rsum[6] + rsum[7];
        if (s > 0) {
            p = dred + bouts + p;          // pred_{s-1}
            float d = p - tgt[s];
            lacc += d * d;
        }

        // ---- phase B: h1(s) for units u0,u1 (replicated, deterministic) ----
        {
            uint2 wu = *reinterpret_cast<const uint2*>(&wc4[u0 * 4]);
            float2 w01 = __half22float2(u2h2(wu.x));
            float2 w23 = __half22float2(u2h2(wu.y));
            float gi = hbf(wA0, 0)  + p * w01.x;
            float gf = hbf(wA0, 16) + p * w01.y;
            float gg = hbf(wA0, 32) + p * w23.x;
            float go = hbf(wB0, 0)  + p * w23.y;
            c1a = sigm(gf) * c1a + sigm(gi) * tanh_f(gg);
            h1h[u0] = __float2half(sigm(go) * tanh_f(c1a));
            wu = *reinterpret_cast<const uint2*>(&wc4[u1 * 4]);
            w01 = __half22float2(u2h2(wu.x));
            w23 = __half22float2(u2h2(wu.y));
            gi = hbf(wA1, 0)  + p * w01.x;
            gf = hbf(wA1, 16) + p * w01.y;
            gg = hbf(wA1, 32) + p * w23.x;
            go = hbf(wB1, 0)  + p * w23.y;
            c1b = sigm(gf) * c1b + sigm(gi) * tanh_f(gg);
            h1h[u1] = __float2half(sigm(go) * tanh_f(c1b));
        }
        // deferred drain of the leftover poll pair (retired during phases A/B
        // -> free, unlike r12's on-exit drain); keeps va/vb/wa/wb reserved.
        asm volatile("s_waitcnt vmcnt(0)"
                     : "+v"(va), "+v"(vb), "+v"(wa), "+v"(wb) :: "memory");
        __syncthreads();

        // ---- phase C: dot8 over LDS activations ----
        {
            uint4 h1c[4];
            #pragma unroll
            for (int j = 0; j < 4; ++j)
                h1c[j] = *reinterpret_cast<const uint4*>(&h1h[o8 + j * 256]);
            uint4 fc = *reinterpret_cast<const uint4*>(&fh[o8]);
            float acc = dot8(wf_r, fc, 0.f);
            #pragma unroll
            for (int j = 0; j < 4; ++j)
                acc = dot8(w1h_r[j], h1c[j], acc);
            float a2 = 0.f;
            #pragma unroll
            for (int j = 0; j < 4; ++j)
                a2 = dot8(w2i_r[j], h1c[j], a2);
            #pragma unroll
            for (int j = 0; j < 4; ++j) {
                uint4 hc = *reinterpret_cast<const uint4*>(&h2h[o8 + j * 256]);
                a2 = dot8(w2h_r[j], hc, a2);
            }
            #pragma unroll
            for (int m = 1; m <= 16; m <<= 1) {
                acc += __shfl_xor(acc, m);
                a2  += __shfl_xor(a2, m);
            }
            if (sub == 0) { g1s[lr] = acc + b1s[lr]; g2s[lr] = a2 + b2s[lr]; }
        }
        __syncthreads();

        // ---- publish: tid<4 layer-2 cell + pack + ONE 16B coherent store ----
        if (tid < 4) {
            float gi2 = sigm(g2s[tid]);
            float gf2 = sigm(g2s[4 + tid]);
            float gg2 = tanh_f(g2s[8 + tid]);
            float go2 = sigm(g2s[12 + tid]);
            c2v = gf2 * c2v + gi2 * gg2;
            float h2n = go2 * tanh_f(c2v);
            const u64 ep = (u64)(unsigned)(s + 1) << 48;
            u64 A = f2hb(g1s[tid]) | (f2hb(g1s[4 + tid]) << 16)
                  | (f2hb(g1s[8 + tid]) << 32) | ep;
            u64 B = f2hb(g1s[12 + tid]) | (f2hb(h2n) << 16) | ep;
            cstore4((unsigned long long)(wq + (size_t)((s + 1) & 1) * 2048
                                            + (size_t)(b4 + tid) * 2), A, B);
        }
    }

    // ---- epilogue: poll pairs (ep == NSLOT), final pred + loss ----
    {
        const int par = NSLOT & 1;  // 1
        const int u0 = tid, u1 = tid + NTHR;
        u64 wB0, wB1;
        {
            const u64* q = wq + (size_t)par * 2048;
            const unsigned long long a0 = (unsigned long long)(q + 2 * (size_t)u0);
            const unsigned long long a1 = (unsigned long long)(q + 2 * (size_t)u1);
            const unsigned need = (unsigned)NSLOT;
            uv4 va, vb;
            unsigned it = 0;
            for (;;) {
                cpoll2(a0, a1, va, vb);
                if (((va[3] >> 16) == need) && ((vb[3] >> 16) == need)) break;
                __builtin_amdgcn_s_sleep(1);
                if (((++it) & 255u) == 0u) {
                    if (__hip_atomic_load(abop, __ATOMIC_RELAXED, __HIP_MEMORY_SCOPE_AGENT) != 0u
                        || it > (1u << 15)) {
                        __hip_atomic_store(abop, 1u, __ATOMIC_RELAXED, __HIP_MEMORY_SCOPE_AGENT);
                        s_bad = 1u;
                        break;
                    }
                }
            }
            wB0 = (u64)va[2] | ((u64)va[3] << 32);
            wB1 = (u64)vb[2] | ((u64)vb[3] << 32);
        }
        float h2v0 = hbf(wB0, 16);
        float h2v1 = hbf(wB1, 16);
        float pp = wout_s[u0] * h2v0 + wout_s[u1] * h2v1;
        #pragma unroll
        for (int m = 1; m <= 32; m <<= 1) pp += __shfl_xor(pp, m);
        if ((tid & 63) == 0) rsum[tid >> 6] = pp;
        __syncthreads();
        if (s_bad != 0u) return;
        float dred = rsum[0] + rsum[1] + rsum[2] + rsum[3]
                   + rsum[4] + rsum[5] + rsum[6] + rsum[7];
        p = dred + bouts + p;
        float d = p - tgt[LN - 1];
        lacc += d * d;
        if (blockIdx.x == 0 && tid == 0) out[0] = sqrtf(lacc / (float)LN);
    }
}

extern "C" void kernel_launch(void* const* d_in, const int* in_sizes, int n_in,
                              void* d_out, int out_size, void* d_ws, size_t ws_size,
                              hipStream_t stream) {
    (void)in_sizes; (void)n_in; (void)out_size; (void)ws_size;
    const float* feat = (const float*)d_in[0];
    const float* tgt  = (const float*)d_in[1];
    const float* Wih1 = (const float*)d_in[2];
    const float* bih1 = (const float*)d_in[3];
    const float* Whh1 = (const float*)d_in[4];
    const float* bhh1 = (const float*)d_in[5];
    const float* Wih2 = (const float*)d_in[6];
    const float* bih2 = (const float*)d_in[7];
    const float* Whh2 = (const float*)d_in[8];
    const float* bhh2 = (const float*)d_in[9];
    const float* Wout = (const float*)d_in[10];
    const float* bout = (const float*)d_in[11];
    float* out = (float*)d_out;
    float* ws  = (float*)d_ws;

    hipLaunchKernelGGL(ws_init, dim3(1), dim3(64), 0, stream, ws);

    const float *a0 = feat, *a1 = tgt, *a2 = Wih1, *a3 = bih1, *a4 = Whh1, *a5 = bhh1,
                *a6 = Wih2, *a7 = bih2, *a8 = Whh2, *a9 = bhh2, *a10 = Wout, *a11 = bout;
    float *a12 = out, *a13 = ws;
    void* args[] = { &a0, &a1, &a2, &a3, &a4, &a5, &a6, &a7, &a8, &a9, &a10, &a11, &a12, &a13 };
    hipError_t e = hipLaunchCooperativeKernel((void*)lstm_main, dim3(NBLK), dim3(NTHR),
                                              args, 0, stream);
    if (e != hipSuccess) {
        hipLaunchKernelGGL(lstm_main, dim3(NBLK), dim3(NTHR), 0, stream,
                           feat, tgt, Wih1, bih1, Whh1, bhh1, Wih2, bih2, Whh2, bhh2,
                           Wout, bout, out, ws);
    }
}

// Round 16
// 14785.664 us; speedup vs baseline: 1.3701x; 1.3701x over previous
//
#include <hip/hip_runtime.h>
#include <hip/hip_fp16.h>
#include <math.h>

#define HN 1024
#define FN 256
#define LN 4096
#define NBLK 256
#define NTHR 512
#define NSLOT (LN - 1)   // 4095 sequential steps

// ws layout (u64 indices):
//   wq[2][1024][2]  at 0     : self-tagged per-unit word pairs (4096 u64)
//     wordA = i16 | f16<<16 | g16<<32 | ep16<<48   (pg1 pre-acts of step ep)
//     wordB = o16 | h2_16<<16 | ep16<<48           (o pre-act step ep, h2(ep-1))
//     unit u's pair is 16B-aligned -> polled with ONE global_load_dwordx4
//   abort u32       at u64 index 4608

typedef unsigned long long u64;
typedef unsigned uv4 __attribute__((ext_vector_type(4)));

__device__ __forceinline__ float sigm(float x) { return 1.0f / (1.0f + __expf(-x)); }
__device__ __forceinline__ float tanh_f(float x) {
    x = fminf(fmaxf(x, -15.0f), 15.0f);
    float e = __expf(2.0f * x);
    return (e - 1.0f) / (e + 1.0f);
}
__device__ __forceinline__ u64 f2hb(float x) {
    union { __half h; unsigned short u; } c; c.h = __float2half(x); return (u64)c.u;
}
__device__ __forceinline__ float hbf(u64 w, int sh) {   // fp16 bits [sh,sh+16) -> f32
    union { unsigned short u; __half h; } c; c.u = (unsigned short)(w >> sh);
    return __half2float(c.h);
}
__device__ __forceinline__ __half2 u2h2(unsigned v) {
    union { unsigned u; __half2 h; } c; c.u = v; return c.h;
}
__device__ __forceinline__ unsigned pk2(float a, float b) {
    union { __half2 h; unsigned u; } c; c.h = __floats2half2_rn(a, b); return c.u;
}
__device__ __forceinline__ uint4 pack8(const float* p) {   // 8 f32 -> 8 fp16 (4 VGPRs)
    uint4 r;
    r.x = pk2(p[0], p[1]); r.y = pk2(p[2], p[3]);
    r.z = pk2(p[4], p[5]); r.w = pk2(p[6], p[7]);
    return r;
}
// 8-term fp16 dot via packed v_pk_fma_f16, f32 master accumulate
__device__ __forceinline__ float dot8(uint4 w, uint4 x, float acc) {
    __half2 s = __hmul2(u2h2(w.x), u2h2(x.x));
    s = __hfma2(u2h2(w.y), u2h2(x.y), s);
    s = __hfma2(u2h2(w.z), u2h2(x.z), s);
    s = __hfma2(u2h2(w.w), u2h2(x.w), s);
    return acc + __low2float(s) + __high2float(s);
}

// One coherent 16B load of a unit's {wordA, wordB} pair: single request at the
// coherence point (vs 2 x 8B atomic loads). Tag sits in the high 16 bits of
// each u64 within the SAME cacheline access -> no tearing hazard.
__device__ __forceinline__ void cpoll2(unsigned long long a0, unsigned long long a1,
                                       uv4& va, uv4& vb) {
    asm volatile("global_load_dwordx4 %0, %2, off sc0 sc1\n\t"
                 "global_load_dwordx4 %1, %3, off sc0 sc1\n\t"
                 "s_waitcnt vmcnt(0)"
                 : "=&v"(va), "=&v"(vb)
                 : "v"(a0), "v"(a1)
                 : "memory");
}
__device__ __forceinline__ void cstore4(unsigned long long addr, u64 A, u64 B) {
    uv4 pv;
    pv[0] = (unsigned)A; pv[1] = (unsigned)(A >> 32);
    pv[2] = (unsigned)B; pv[3] = (unsigned)(B >> 32);
    asm volatile("global_store_dwordx4 %0, %1, off sc0 sc1"
                 :: "v"(addr), "v"(pv) : "memory");
}

__global__ void ws_init(float* ws) {
    if (threadIdx.x == 0) *((unsigned*)((u64*)ws + 4608)) = 0u;   // abort flag
}

// 2nd arg = min waves per SIMD(EU): 2 waves/SIMD == 1 block/CU.
__global__ __launch_bounds__(NTHR, 2)
void lstm_main(const float* __restrict__ feat, const float* __restrict__ tgt,
               const float* __restrict__ Wih1, const float* __restrict__ bih1,
               const float* __restrict__ Whh1, const float* __restrict__ bhh1,
               const float* __restrict__ Wih2, const float* __restrict__ bih2,
               const float* __restrict__ Whh2, const float* __restrict__ bhh2,
               const float* __restrict__ Wout, const float* __restrict__ bout,
               float* __restrict__ out, float* __restrict__ ws)
{
    // block b owns units [4b,4b+4) of layer1 (16 gate rows) and layer2.
    // thread: lr = tid>>5 (row 0..15), sub = tid&31 (32-way K-split).
    __shared__ __align__(16) __half wc4[4 * HN];     //  8 KB  W_ih1[:,256], [unit][gate]
    __shared__ __align__(16) float  wout_s[HN];      //  4 KB
    __shared__ __align__(16) __half h1h[HN];         //  2 KB
    __shared__ __align__(16) __half h2h[HN];         //  2 KB
    __shared__ __align__(16) __half fh[FN];          //  0.5 KB
    __shared__ float b1s[16], b2s[16], g1s[16], g2s[16];
    __shared__ float rsum[NTHR / 64];
    __shared__ float bouts;
    __shared__ unsigned s_bad;

    const int tid = threadIdx.x;
    const int b4  = (int)blockIdx.x * 4;
    u64* wq  = (u64*)ws;
    unsigned* abop = (unsigned*)(wq + 4608);

    const int lr  = tid >> 5;          // gate row 0..15 (g*4+ui)
    const int sub = tid & 31;
    const int o8  = sub * 8;
    const int gr  = (lr >> 2) * HN + b4 + (lr & 3);   // global gate row

    // ---------------- prologue: weight slices (cache-served, fp16-packed) ----------------
    uint4 wf_r = pack8(Wih1 + (size_t)gr * (FN + 1) + o8);
    uint4 w1h_r[4], w2i_r[4], w2h_r[4];
    #pragma unroll
    for (int j = 0; j < 4; ++j) {
        const int c0 = o8 + j * 256;
        w1h_r[j] = pack8(Whh1 + (size_t)gr * HN + c0);
        w2i_r[j] = pack8(Wih2 + (size_t)gr * HN + c0);
        w2h_r[j] = pack8(Whh2 + (size_t)gr * HN + c0);
    }
    for (int e = tid; e < 4 * HN; e += NTHR) {
        int u = e >> 2, g = e & 3;
        wc4[e] = __float2half(Wih1[(g * HN + u) * (FN + 1) + FN]);
    }
    for (int e = tid; e < HN; e += NTHR) wout_s[e] = Wout[e];
    if (tid < 16) {
        int grr = (tid >> 2) * HN + b4 + (tid & 3);
        b1s[tid] = bih1[grr] + bhh1[grr];
        b2s[tid] = bih2[grr] + bhh2[grr];
    }
    if (tid == 0) { bouts = bout[0]; s_bad = 0u; }
    if (tid < FN) fh[tid] = __float2half(feat[tid]);
    __syncthreads();

    // priming: pg1(0) = W_ih1[:, :256] @ f_0 + biases  (h1_{-1} = 0)
    {
        uint4 fc = *reinterpret_cast<const uint4*>(&fh[o8]);
        float acc = dot8(wf_r, fc, 0.f);
        #pragma unroll
        for (int m = 1; m <= 16; m <<= 1) acc += __shfl_xor(acc, m);
        if (sub == 0) g1s[lr] = acc + b1s[lr];
    }
    __syncthreads();
    if (tid < 4) {   // publish {pg1(0), h2(-1)=0} ep=0 -> parity 0, one 16B store
        u64 A = f2hb(g1s[tid]) | (f2hb(g1s[4 + tid]) << 16) | (f2hb(g1s[8 + tid]) << 32);
        u64 B = f2hb(g1s[12 + tid]);
        cstore4((unsigned long long)(wq + (size_t)(b4 + tid) * 2), A, B);
    }

    float c1a = 0.f, c1b = 0.f;     // replicated c1 (units tid, tid+512)
    float c2v = 0.f;                // c2 for unit b4+tid (tid<4)
    float p = tgt[0];
    float lacc = 0.f;

    for (int s = 0; s < NSLOT; ++s) {
        const int par = s & 1;
        const int u0 = tid, u1 = tid + NTHR;

        // ---- feature prefetch (hides under the poll) ----
        float fv = (tid < FN) ? feat[(size_t)(s + 1) * FN + tid] : 0.f;

        // ---- self-tagged poll: 2 x b128 coherent loads (issue+wait+check) ----
        u64 wA0, wB0, wA1, wB1;
        {
            const u64* q = wq + (size_t)par * 2048;
            const unsigned long long a0 = (unsigned long long)(q + 2 * (size_t)u0);
            const unsigned long long a1 = (unsigned long long)(q + 2 * (size_t)u1);
            const unsigned need = (unsigned)s;
            uv4 va, vb;
            unsigned it = 0;
            for (;;) {
                cpoll2(a0, a1, va, vb);
                if (((va[1] >> 16) == need) && ((va[3] >> 16) == need) &&
                    ((vb[1] >> 16) == need) && ((vb[3] >> 16) == need)) break;
                __builtin_amdgcn_s_sleep(1);
                if (((++it) & 255u) == 0u) {
                    if (__hip_atomic_load(abop, __ATOMIC_RELAXED, __HIP_MEMORY_SCOPE_AGENT) != 0u
                        || it > (1u << 15)) {
                        __hip_atomic_store(abop, 1u, __ATOMIC_RELAXED, __HIP_MEMORY_SCOPE_AGENT);
                        s_bad = 1u;
                        break;
                    }
                }
            }
            wA0 = (u64)va[0] | ((u64)va[1] << 32);
            wB0 = (u64)va[2] | ((u64)va[3] << 32);
            wA1 = (u64)vb[0] | ((u64)vb[1] << 32);
            wB1 = (u64)vb[2] | ((u64)vb[3] << 32);
        }

        // ---- phase A: stage h2/f to LDS, pred(s-1) from local wout dot ----
        float h2v0 = hbf(wB0, 16);
        float h2v1 = hbf(wB1, 16);
        h2h[u0] = __float2half(h2v0);
        h2h[u1] = __float2half(h2v1);
        if (tid < FN) fh[tid] = __float2half(fv);
        float pp = wout_s[u0] * h2v0 + wout_s[u1] * h2v1;
        #pragma unroll
        for (int m = 1; m <= 32; m <<= 1) pp += __shfl_xor(pp, m);
        if ((tid & 63) == 0) rsum[tid >> 6] = pp;
        __syncthreads();
        if (s_bad != 0u) return;
        float dred = rsum[0] + rsum[1] + rsum[2] + rsum[3]
                   + rsum[4] + rsum[5] + rsum[6] + rsum[7];
        if (s > 0) {
            p = dred + bouts + p;          // pred_{s-1}
            float d = p - tgt[s];
            lacc += d * d;
        }

        // ---- phase B: h1(s) for units u0,u1 (replicated, deterministic) ----
        {
            uint2 wu = *reinterpret_cast<const uint2*>(&wc4[u0 * 4]);
            float2 w01 = __half22float2(u2h2(wu.x));
            float2 w23 = __half22float2(u2h2(wu.y));
            float gi = hbf(wA0, 0)  + p * w01.x;
            float gf = hbf(wA0, 16) + p * w01.y;
            float gg = hbf(wA0, 32) + p * w23.x;
            float go = hbf(wB0, 0)  + p * w23.y;
            c1a = sigm(gf) * c1a + sigm(gi) * tanh_f(gg);
            h1h[u0] = __float2half(sigm(go) * tanh_f(c1a));
            wu = *reinterpret_cast<const uint2*>(&wc4[u1 * 4]);
            w01 = __half22float2(u2h2(wu.x));
            w23 = __half22float2(u2h2(wu.y));
            gi = hbf(wA1, 0)  + p * w01.x;
            gf = hbf(wA1, 16) + p * w01.y;
            gg = hbf(wA1, 32) + p * w23.x;
            go = hbf(wB1, 0)  + p * w23.y;
            c1b = sigm(gf) * c1b + sigm(gi) * tanh_f(gg);
            h1h[u1] = __float2half(sigm(go) * tanh_f(c1b));
        }
        __syncthreads();

        // ---- phase C: dot8 over LDS activations ----
        {
            uint4 h1c[4];
            #pragma unroll
            for (int j = 0; j < 4; ++j)
                h1c[j] = *reinterpret_cast<const uint4*>(&h1h[o8 + j * 256]);
            uint4 fc = *reinterpret_cast<const uint4*>(&fh[o8]);
            float acc = dot8(wf_r, fc, 0.f);
            #pragma unroll
            for (int j = 0; j < 4; ++j)
                acc = dot8(w1h_r[j], h1c[j], acc);
            float a2 = 0.f;
            #pragma unroll
            for (int j = 0; j < 4; ++j)
                a2 = dot8(w2i_r[j], h1c[j], a2);
            #pragma unroll
            for (int j = 0; j < 4; ++j) {
                uint4 hc = *reinterpret_cast<const uint4*>(&h2h[o8 + j * 256]);
                a2 = dot8(w2h_r[j], hc, a2);
            }
            #pragma unroll
            for (int m = 1; m <= 16; m <<= 1) {
                acc += __shfl_xor(acc, m);
                a2  += __shfl_xor(a2, m);
            }
            if (sub == 0) { g1s[lr] = acc + b1s[lr]; g2s[lr] = a2 + b2s[lr]; }
        }
        __syncthreads();

        // ---- publish: tid<4 layer-2 cell + pack + ONE 16B coherent store ----
        if (tid < 4) {
            float gi2 = sigm(g2s[tid]);
            float gf2 = sigm(g2s[4 + tid]);
            float gg2 = tanh_f(g2s[8 + tid]);
            float go2 = sigm(g2s[12 + tid]);
            c2v = gf2 * c2v + gi2 * gg2;
            float h2n = go2 * tanh_f(c2v);
            const u64 ep = (u64)(unsigned)(s + 1) << 48;
            u64 A = f2hb(g1s[tid]) | (f2hb(g1s[4 + tid]) << 16)
                  | (f2hb(g1s[8 + tid]) << 32) | ep;
            u64 B = f2hb(g1s[12 + tid]) | (f2hb(h2n) << 16) | ep;
            cstore4((unsigned long long)(wq + (size_t)((s + 1) & 1) * 2048
                                            + (size_t)(b4 + tid) * 2), A, B);
        }
    }

    // ---- epilogue: poll pairs (ep == NSLOT), final pred + loss ----
    {
        const int par = NSLOT & 1;  // 1
        const int u0 = tid, u1 = tid + NTHR;
        u64 wB0, wB1;
        {
            const u64* q = wq + (size_t)par * 2048;
            const unsigned long long a0 = (unsigned long long)(q + 2 * (size_t)u0);
            const unsigned long long a1 = (unsigned long long)(q + 2 * (size_t)u1);
            const unsigned need = (unsigned)NSLOT;
            uv4 va, vb;
            unsigned it = 0;
            for (;;) {
                cpoll2(a0, a1, va, vb);
                if (((va[3] >> 16) == need) && ((vb[3] >> 16) == need)) break;
                __builtin_amdgcn_s_sleep(1);
                if (((++it) & 255u) == 0u) {
                    if (__hip_atomic_load(abop, __ATOMIC_RELAXED, __HIP_MEMORY_SCOPE_AGENT) != 0u
                        || it > (1u << 15)) {
                        __hip_atomic_store(abop, 1u, __ATOMIC_RELAXED, __HIP_MEMORY_SCOPE_AGENT);
                        s_bad = 1u;
                        break;
                    }
                }
            }
            wB0 = (u64)va[2] | ((u64)va[3] << 32);
            wB1 = (u64)vb[2] | ((u64)vb[3] << 32);
        }
        float h2v0 = hbf(wB0, 16);
        float h2v1 = hbf(wB1, 16);
        float pp = wout_s[u0] * h2v0 + wout_s[u1] * h2v1;
        #pragma unroll
        for (int m = 1; m <= 32; m <<= 1) pp += __shfl_xor(pp, m);
        if ((tid & 63) == 0) rsum[tid >> 6] = pp;
        __syncthreads();
        if (s_bad != 0u) return;
        float dred = rsum[0] + rsum[1] + rsum[2] + rsum[3]
                   + rsum[4] + rsum[5] + rsum[6] + rsum[7];
        p = dred + bouts + p;
        float d = p - tgt[LN - 1];
        lacc += d * d;
        if (blockIdx.x == 0 && tid == 0) out[0] = sqrtf(lacc / (float)LN);
    }
}

extern "C" void kernel_launch(void* const* d_in, const int* in_sizes, int n_in,
                              void* d_out, int out_size, void* d_ws, size_t ws_size,
                              hipStream_t stream) {
    (void)in_sizes; (void)n_in; (void)out_size; (void)ws_size;
    const float* feat = (const float*)d_in[0];
    const float* tgt  = (const float*)d_in[1];
    const float* Wih1 = (const float*)d_in[2];
    const float* bih1 = (const float*)d_in[3];
    const float* Whh1 = (const float*)d_in[4];
    const float* bhh1 = (const float*)d_in[5];
    const float* Wih2 = (const float*)d_in[6];
    const float* bih2 = (const float*)d_in[7];
    const float* Whh2 = (const float*)d_in[8];
    const float* bhh2 = (const float*)d_in[9];
    const float* Wout = (const float*)d_in[10];
    const float* bout = (const float*)d_in[11];
    float* out = (float*)d_out;
    float* ws  = (float*)d_ws;

    hipLaunchKernelGGL(ws_init, dim3(1), dim3(64), 0, stream, ws);

    const float *a0 = feat, *a1 = tgt, *a2 = Wih1, *a3 = bih1, *a4 = Whh1, *a5 = bhh1,
                *a6 = Wih2, *a7 = bih2, *a8 = Whh2, *a9 = bhh2, *a10 = Wout, *a11 = bout;
    float *a12 = out, *a13 = ws;
    void* args[] = { &a0, &a1, &a2, &a3, &a4, &a5, &a6, &a7, &a8, &a9, &a10, &a11, &a12, &a13 };
    hipError_t e = hipLaunchCooperativeKernel((void*)lstm_main, dim3(NBLK), dim3(NTHR),
                                              args, 0, stream);
    if (e != hipSuccess) {
        hipLaunchKernelGGL(lstm_main, dim3(NBLK), dim3(NTHR), 0, stream,
                           feat, tgt, Wih1, bih1, Whh1, bhh1, Wih2, bih2, Whh2, bhh2,
                           Wout, bout, out, ws);
    }
}